// Round 7
// baseline (263.926 us; speedup 1.0000x reference)
//
#include <hip/hip_runtime.h>

// ---------------------------------------------------------------------------
// Capsule cell, bf16-MFMA v2.
//   conv0 (1x1, fp32 VALU)          -> h0t  bf16 [B][L][64]
//   conv1 (k=9, MFMA 16x16x32 bf16) -> h1   fp32 [B][L][512]
//   squash                          -> h1sq bf16 [b][n][cc 8][ln 256][72pad]
//   conv2 (k=3x512, MFMA, v2)       -> V    fp32 [B][LN][N][256]
//   routing (3 iters, fp32)         -> out  [B][LN*16][16]
// conv2 v2: one block per (b,n), tile 256o x 256ln, 8 cc-phases; per phase
// stage Hc(258x72) + W(3g x 256o x 72) once via global_load_lds(16B), then
// 192 MFMA between barriers (was 32).  LDS 147.7 KB -> 1 block/CU, grid 256.
// Padded-72 rows: gload_lds writes linear; pads copied but never read
// (frags touch shorts [0,64) only).  144B row stride -> 2-way bank alias, free.
// ---------------------------------------------------------------------------

#define LL    2048
#define NCAP  8
#define CO1   512
#define CO2   256
#define LNN   256

typedef __attribute__((ext_vector_type(8))) short bhalf8;   // 8 bf16 (4 VGPR)
typedef __attribute__((ext_vector_type(4))) float facc4;    // MFMA accumulator

#define MFMA16(a, b, c) __builtin_amdgcn_mfma_f32_16x16x32_bf16(a, b, c, 0, 0, 0)

__device__ inline unsigned short f2bf(float f) {   // round-to-nearest-even
  unsigned u = __float_as_uint(f);
  return (unsigned short)((u + 0x7FFFu + ((u >> 16) & 1u)) >> 16);
}

#if __has_builtin(__builtin_amdgcn_global_load_lds)
#define HAVE_GLDS 1
#else
#define HAVE_GLDS 0
#endif

// copy 1024B: per-lane global src (base + lane*16B), wave-uniform LDS dest.
__device__ __forceinline__ void g2l16(const unsigned short* g, unsigned short* l,
                                      int lane) {
#if HAVE_GLDS
  __builtin_amdgcn_global_load_lds(
      (const __attribute__((address_space(1))) void*)(g + lane * 8),
      (__attribute__((address_space(3))) void*)l, 16, 0, 0);
#else
  *(bhalf8*)(l + lane * 8) = *(const bhalf8*)(g + lane * 8);
#endif
}

// ws offsets (bytes); end 219,578,368 <= 220,856,320 proven available (r3)
#define OFF_W1TB 0u            // 9*512*64 bf16            = 589824
#define OFF_W2P  589824u       // 8cc*3g*256o*72 bf16      = 884736
#define OFF_H0T  1474560u      // 32*2048*64 bf16          = 8388608
#define OFF_H1   9863168u      // 32*2048*512 fp32         = 134217728 ; V aliases
#define OFF_H1SQ 144080896u    // 32*8*8*256*72 bf16       = 75497472

// ---------------- prep: weights -> bf16 -------------------------------------
// w1tb[g][co][cb64] = bf16(w1[co][cb][g]); w2p[cc][g][o][72] = bf16(w2[o][g][c])
__global__ __launch_bounds__(256) void prep_kernel(
    const float* __restrict__ w1, const float* __restrict__ w2,
    unsigned short* __restrict__ w1tb, unsigned short* __restrict__ w2p) {
  int idx = blockIdx.x * 256 + threadIdx.x;
  if (idx < 294912) {                    // 9*512*64
    int cb = idx & 63;
    int co = (idx >> 6) & 511;
    int g  = idx >> 15;
    w1tb[idx] = f2bf(w1[(co * 64 + cb) * 9 + g]);
  } else {
    int j = idx - 294912;                // 8*3*256*64 = 393216 tasks
    int ci = j & 63;
    int t  = j >> 6;
    int o  = t & 255;
    t >>= 8;                             // t in [0,24)
    int g  = t % 3;
    int cc = t / 3;
    w2p[((cc * 3 + g) * 256 + o) * 72 + ci] =
        f2bf(w2[(o * 3 + g) * 512 + cc * 64 + ci]);
  }
}

// ---------------- conv0: 1x1, x[B][64][L] -> h0t bf16 [B][L][64] ------------
__global__ __launch_bounds__(256) void conv0_kernel(
    const float* __restrict__ x, const float* __restrict__ w0,
    const float* __restrict__ b0, unsigned short* __restrict__ h0t) {
  __shared__ __align__(16) float xt[64][128];
  __shared__ __align__(16) float w0t[64][68];
  int tid = threadIdx.x;
  int b = blockIdx.y;
  int l0 = blockIdx.x * 128;
  const float* xb = x + (size_t)b * 64 * LL;
#pragma unroll
  for (int i = 0; i < 8; i++) {
    int idx = i * 256 + tid;
    int k = idx >> 5, l4 = idx & 31;
    float4 v = *(const float4*)&xb[k * LL + l0 + l4 * 4];
    *(float4*)&xt[k][l4 * 4] = v;
  }
#pragma unroll
  for (int i = 0; i < 16; i++) {
    int idx = i * 256 + tid;
    int cb = idx >> 6, k = idx & 63;
    w0t[k][cb] = w0[idx];
  }
  __syncthreads();
  int lc = tid & 31, rc = tid >> 5;             // l=lc*4+j, cb=rc*8+i
  float acc[8][4] = {};
  for (int k = 0; k < 64; k++) {
    float4 bv = *(const float4*)&xt[k][lc * 4];
    float4 a0 = *(const float4*)&w0t[k][rc * 8];
    float4 a1 = *(const float4*)&w0t[k][rc * 8 + 4];
    float a[8] = {a0.x, a0.y, a0.z, a0.w, a1.x, a1.y, a1.z, a1.w};
    float bb4[4] = {bv.x, bv.y, bv.z, bv.w};
#pragma unroll
    for (int i = 0; i < 8; i++)
#pragma unroll
      for (int j = 0; j < 4; j++) acc[i][j] += a[i] * bb4[j];
  }
  float bias[8];
#pragma unroll
  for (int i = 0; i < 8; i++) bias[i] = b0[rc * 8 + i];
#pragma unroll
  for (int j = 0; j < 4; j++) {
    bhalf8 o;
#pragma unroll
    for (int i = 0; i < 8; i++) o[i] = (short)f2bf(acc[i][j] + bias[i]);
    *(bhalf8*)&h0t[((size_t)b * LL + l0 + lc * 4 + j) * 64 + rc * 8] = o;
  }
}

// ---------------- conv1: k=9, 64->512, MFMA (unchanged from r6) -------------
__global__ __launch_bounds__(512) void conv1_mfma(
    const unsigned short* __restrict__ h0t, const unsigned short* __restrict__ w1tb,
    const float* __restrict__ b1, float* __restrict__ h1) {
  __shared__ __align__(16) unsigned short Xt[136 * 72];
  __shared__ __align__(16) unsigned short Wg[256 * 72];
  int tid = threadIdx.x;
  int b = blockIdx.z;
  int co0 = blockIdx.y * 256;
  int l0 = blockIdx.x * 128;
#pragma unroll
  for (int it = 0; it < 3; it++) {
    int idx = it * 512 + tid;
    if (idx < 1088) {
      int row = idx >> 3, c8 = (idx & 7) * 8;
      int l = l0 - 4 + row;
      bhalf8 v = (bhalf8)0;
      if (l >= 0 && l < LL) v = *(const bhalf8*)&h0t[((size_t)b * LL + l) * 64 + c8];
      *(bhalf8*)&Xt[row * 72 + c8] = v;
    }
  }
  int wid = tid >> 6, lane = tid & 63;
  int wr = wid >> 1, wc = wid & 1;
  int r16 = lane & 15, k8 = lane >> 4;
  facc4 acc[4][4] = {};
  for (int g = 0; g < 9; g++) {
    __syncthreads();
#pragma unroll
    for (int it = 0; it < 4; it++) {
      int idx = it * 512 + tid;
      int row = idx >> 3, c8 = (idx & 7) * 8;
      *(bhalf8*)&Wg[row * 72 + c8] =
          *(const bhalf8*)&w1tb[((size_t)(g * 512 + co0 + row)) * 64 + c8];
    }
    __syncthreads();
#pragma unroll
    for (int ks = 0; ks < 2; ks++) {
      bhalf8 A[4], Bf[4];
#pragma unroll
      for (int mi = 0; mi < 4; mi++)
        A[mi] = *(const bhalf8*)&Wg[(wr * 64 + mi * 16 + r16) * 72 + ks * 32 + k8 * 8];
#pragma unroll
      for (int ni = 0; ni < 4; ni++)
        Bf[ni] = *(const bhalf8*)&Xt[(wc * 64 + ni * 16 + r16 + g) * 72 + ks * 32 + k8 * 8];
#pragma unroll
      for (int mi = 0; mi < 4; mi++)
#pragma unroll
        for (int ni = 0; ni < 4; ni++)
          acc[mi][ni] = MFMA16(A[mi], Bf[ni], acc[mi][ni]);
    }
  }
#pragma unroll
  for (int mi = 0; mi < 4; mi++) {
    int co_w = co0 + wr * 64 + mi * 16 + k8 * 4;
    float4 bias = *(const float4*)&b1[co_w];
#pragma unroll
    for (int ni = 0; ni < 4; ni++) {
      int l_w = l0 + wc * 64 + ni * 16 + r16;
      float* p = &h1[((size_t)b * LL + l_w) * CO1 + co_w];
      *(float4*)p = make_float4(acc[mi][ni][0] + bias.x, acc[mi][ni][1] + bias.y,
                                acc[mi][ni][2] + bias.z, acc[mi][ni][3] + bias.w);
    }
  }
}

// ---------------- squash: h1 fp32 -> h1sq bf16 [b][n][cc][ln][72] -----------
__global__ __launch_bounds__(256) void squash1_kernel(
    const float* __restrict__ h1, unsigned short* __restrict__ h1sq) {
  int tid = threadIdx.x;
  int wave = tid >> 6, lane = tid & 63;
  size_t row = (size_t)blockIdx.x * 4 + wave;      // b*L + l
  const float* p = h1 + row * CO1;
  float4 v0 = *(const float4*)(p + lane * 8);
  float4 v1 = *(const float4*)(p + lane * 8 + 4);
  float sq = v0.x * v0.x + v0.y * v0.y + v0.z * v0.z + v0.w * v0.w +
             v1.x * v1.x + v1.y * v1.y + v1.z * v1.z + v1.w * v1.w;
#pragma unroll
  for (int m = 1; m < 64; m <<= 1) sq += __shfl_xor(sq, m, 64);
  float s = sq / (1.f + sq) / sqrtf(sq + 1e-8f);
  bhalf8 o;
  o[0] = (short)f2bf(v0.x * s); o[1] = (short)f2bf(v0.y * s);
  o[2] = (short)f2bf(v0.z * s); o[3] = (short)f2bf(v0.w * s);
  o[4] = (short)f2bf(v1.x * s); o[5] = (short)f2bf(v1.y * s);
  o[6] = (short)f2bf(v1.z * s); o[7] = (short)f2bf(v1.w * s);
  int b = (int)(row >> 11), l = (int)(row & 2047);
  int ln = l >> 3, n = l & 7;
  int cc = lane >> 3, ci8 = (lane & 7) * 8;
  *(bhalf8*)&h1sq[((size_t)(((b * 8 + n) * 8 + cc) * 256 + ln)) * 72 + ci8] = o;
}

// ---------------- conv2 v2: per (b,n), 256o x 256ln, 8 cc-phases ------------
__global__ __launch_bounds__(512, 2) void conv2_mfma(
    const unsigned short* __restrict__ h1sq, const unsigned short* __restrict__ w2p,
    const float* __restrict__ b2, float* __restrict__ V) {
  __shared__ __align__(16) unsigned short Hc[258 * 72];    // row r <-> ln = r-1
  __shared__ __align__(16) unsigned short Wl[3 * 256 * 72];
  int tid = threadIdx.x;
  int bn = blockIdx.x;
  int b = bn >> 3, n = bn & 7;
  int wid = tid >> 6, lane = tid & 63;
  int wr = wid >> 2, wc = wid & 3;                 // 2 o-halves x 4 ln-quarters
  int r16 = lane & 15, k8 = lane >> 4;
  facc4 acc[8][4] = {};                            // 128 VGPR
  for (int cc = 0; cc < 8; cc++) {
    __syncthreads();                               // prev MFMA done before overwrite
    if (tid < 72) { Hc[tid] = 0; Hc[257 * 72 + tid] = 0; }   // ln=-1, ln=256
    const unsigned short* hsrc = h1sq + (size_t)((b * 8 + n) * 8 + cc) * (256 * 72);
    for (int ch = wid; ch < 36; ch += 8)           // rows 1..256: 36 KB bulk
      g2l16(hsrc + ch * 512, &Hc[72 + ch * 512], lane);
    const unsigned short* wsrc = w2p + (size_t)cc * (3 * 256 * 72);
    for (int ch = wid; ch < 108; ch += 8)          // 3g x 256o slice: 108 KB
      g2l16(wsrc + ch * 512, &Wl[ch * 512], lane);
    __syncthreads();                               // drains vmcnt + lgkm
    for (int g = 0; g < 3; g++) {
#pragma unroll
      for (int ks = 0; ks < 2; ks++) {
        bhalf8 Bv[4];
#pragma unroll
        for (int ni = 0; ni < 4; ni++)             // B row = ln_w + g (pad 1)
          Bv[ni] = *(const bhalf8*)&Hc[(wc * 64 + ni * 16 + r16 + g) * 72 + ks * 32 + k8 * 8];
#pragma unroll
        for (int mi = 0; mi < 8; mi++) {
          bhalf8 Av = *(const bhalf8*)&Wl[(g * 256 + wr * 128 + mi * 16 + r16) * 72 + ks * 32 + k8 * 8];
#pragma unroll
          for (int ni = 0; ni < 4; ni++)
            acc[mi][ni] = MFMA16(Av, Bv[ni], acc[mi][ni]);
        }
      }
    }
  }
#pragma unroll
  for (int mi = 0; mi < 8; mi++) {
    int o_w = wr * 128 + mi * 16 + k8 * 4;
    float4 bias = *(const float4*)&b2[o_w];
#pragma unroll
    for (int ni = 0; ni < 4; ni++) {
      int ln_w = wc * 64 + ni * 16 + r16;
      float* p = &V[(((size_t)b * LNN + ln_w) * NCAP + n) * CO2 + o_w];
      *(float4*)p = make_float4(acc[mi][ni][0] + bias.x, acc[mi][ni][1] + bias.y,
                                acc[mi][ni][2] + bias.z, acc[mi][ni][3] + bias.w);
    }
  }
}

// ---------------- dynamic routing: one block per (b,ln) ---------------------
__global__ __launch_bounds__(256) void routing_kernel(
    const float* __restrict__ V, float* __restrict__ out) {
  __shared__ float Vs[8][16][17];
  __shared__ float blog[8][16];
  __shared__ float cbuf[8][16];
  __shared__ float vbuf[16][17];
  int tid = threadIdx.x;
  size_t base = (size_t)blockIdx.x * 2048;
#pragma unroll
  for (int i = 0; i < 8; i++) {
    int idx = i * 256 + tid;
    int nn = idx >> 8, r = idx & 255;
    Vs[nn][r >> 4][r & 15] = V[base + idx];
  }
  if (tid < 128) blog[tid >> 4][tid & 15] = 0.f;
  __syncthreads();
  int csb = tid >> 4, asb = tid & 15;
  for (int r = 0; r < 3; r++) {
    if (tid < 128) {                     // softmax over csb (lane%16 = csb)
      int nn = tid >> 4, cs = tid & 15;
      float xv = blog[nn][cs];
      float m = xv;
#pragma unroll
      for (int d = 1; d < 16; d <<= 1) m = fmaxf(m, __shfl_xor(m, d, 16));
      float e = expf(xv - m);
      float ssum = e;
#pragma unroll
      for (int d = 1; d < 16; d <<= 1) ssum += __shfl_xor(ssum, d, 16);
      cbuf[nn][cs] = e / ssum;
    }
    __syncthreads();
    float s = 0.f;                       // s[csb][asb] = sum_n c*V
#pragma unroll
    for (int q = 0; q < 8; q++) s += cbuf[q][csb] * Vs[q][csb][asb];
    float sq = s * s;                    // reduce over asb
#pragma unroll
    for (int d = 1; d < 16; d <<= 1) sq += __shfl_xor(sq, d, 16);
    float vv = s * (sq / (1.f + sq) / sqrtf(sq + 1e-8f));
    if (r < 2) {
      vbuf[csb][asb] = vv;
      __syncthreads();
      if (tid < 128) {                   // a[n][csb] = sum_asb V*v
        int nn = tid >> 4, cs = tid & 15;
        float a = 0.f;
#pragma unroll
        for (int q = 0; q < 16; q++) a += Vs[nn][cs][q] * vbuf[cs][q];
        blog[nn][cs] += a;
      }
      __syncthreads();
    } else {
      out[(size_t)blockIdx.x * 256 + tid] = vv;
    }
  }
}

extern "C" void kernel_launch(void* const* d_in, const int* in_sizes, int n_in,
                              void* d_out, int out_size, void* d_ws, size_t ws_size,
                              hipStream_t stream) {
  const float* x  = (const float*)d_in[0];
  const float* w0 = (const float*)d_in[1];
  const float* b0 = (const float*)d_in[2];
  const float* w1 = (const float*)d_in[3];
  const float* b1 = (const float*)d_in[4];
  const float* w2 = (const float*)d_in[5];
  const float* b2 = (const float*)d_in[6];
  float* out = (float*)d_out;
  char* ws = (char*)d_ws;
  unsigned short* w1tb = (unsigned short*)(ws + OFF_W1TB);
  unsigned short* w2p  = (unsigned short*)(ws + OFF_W2P);
  unsigned short* h0t  = (unsigned short*)(ws + OFF_H0T);
  float*          h1   = (float*)(ws + OFF_H1);
  unsigned short* h1sq = (unsigned short*)(ws + OFF_H1SQ);
  float*          Vb   = (float*)(ws + OFF_H1);   // aliases h1 (dead after squash)

  prep_kernel<<<2688, 256, 0, stream>>>(w1, w2, w1tb, w2p);
  conv0_kernel<<<dim3(16, 32), 256, 0, stream>>>(x, w0, b0, h0t);
  conv1_mfma<<<dim3(16, 2, 32), 512, 0, stream>>>(h0t, w1tb, b1, h1);
  squash1_kernel<<<16384, 256, 0, stream>>>(h1, h1sq);
  conv2_mfma<<<256, 512, 0, stream>>>(h1sq, w2p, b2, Vb);
  routing_kernel<<<8192, 256, 0, stream>>>(Vb, out);
}